// Round 1
// baseline (30.856 us; speedup 1.0000x reference)
//
#include <hip/hip_runtime.h>

// MedianFilter2D: 3x3 median, reflect padding, input [16,3,512,512] f32.
// Exact separable identity: per column sorted triple (min,med,max);
// median9 = med3( max3(col mins), med3(col meds), min3(col maxs) ).
// Each thread computes 4 consecutive outputs in one row (float4 I/O).

constexpr int Wd = 512;
constexpr int Hd = 512;

__device__ __forceinline__ float med3f(float a, float b, float c) {
    return __builtin_amdgcn_fmed3f(a, b, c);
}
__device__ __forceinline__ float min3f(float a, float b, float c) {
    return fminf(fminf(a, b), c);   // clang folds to v_min3_f32
}
__device__ __forceinline__ float max3f(float a, float b, float c) {
    return fmaxf(fmaxf(a, b), c);   // clang folds to v_max3_f32
}

__global__ __launch_bounds__(256) void MedianFilter2D_68745246540291_kernel(
    const float* __restrict__ in, float* __restrict__ out, int total4) {
    int idx = blockIdx.x * blockDim.x + threadIdx.x;
    if (idx >= total4) return;

    int w4   = (idx & 127) << 2;          // column base, multiple of 4 (W/4 = 128)
    int row  = idx >> 7;                  // global row index in [0, B*C*H)
    int h    = row & (Hd - 1);
    long plane = (long)(row >> 9);        // H = 512 = 2^9

    const float* p = in + plane * (long)(Hd * Wd);
    // reflect rows: padded -1 -> 1, padded H -> H-2
    int hm = (h == 0)      ? 1      : h - 1;
    int hp = (h == Hd - 1) ? Hd - 2 : h + 1;

    const float* rows[3] = { p + (long)hm * Wd, p + (long)h * Wd, p + (long)hp * Wd };

    // v[r][0..5] = columns w4-1 .. w4+4 of row r (reflect on columns)
    float v[3][6];
#pragma unroll
    for (int r = 0; r < 3; ++r) {
        const float* rp = rows[r];
        float4 c4 = *reinterpret_cast<const float4*>(rp + w4);
        v[r][1] = c4.x; v[r][2] = c4.y; v[r][3] = c4.z; v[r][4] = c4.w;
        v[r][0] = (w4 == 0)          ? rp[1]      : rp[w4 - 1];
        v[r][5] = (w4 + 4 >= Wd)     ? rp[Wd - 2] : rp[w4 + 4];
    }

    // sorted triple per column
    float cmin[6], cmed[6], cmax[6];
#pragma unroll
    for (int c = 0; c < 6; ++c) {
        cmin[c] = min3f(v[0][c], v[1][c], v[2][c]);
        cmed[c] = med3f(v[0][c], v[1][c], v[2][c]);
        cmax[c] = max3f(v[0][c], v[1][c], v[2][c]);
    }

    float4 o;
    float* op = &o.x;
#pragma unroll
    for (int j = 0; j < 4; ++j) {
        float lo = max3f(cmin[j], cmin[j + 1], cmin[j + 2]);
        float mi = med3f(cmed[j], cmed[j + 1], cmed[j + 2]);
        float hi = min3f(cmax[j], cmax[j + 1], cmax[j + 2]);
        op[j] = med3f(lo, mi, hi);
    }

    *reinterpret_cast<float4*>(out + (long)row * Wd + w4) = o;
}

extern "C" void kernel_launch(void* const* d_in, const int* in_sizes, int n_in,
                              void* d_out, int out_size, void* d_ws, size_t ws_size,
                              hipStream_t stream) {
    const float* in = (const float*)d_in[0];
    float* out = (float*)d_out;
    int total4 = out_size / 4;                 // 4 outputs per thread
    int block = 256;
    int grid = (total4 + block - 1) / block;   // 12288 blocks
    MedianFilter2D_68745246540291_kernel<<<grid, block, 0, stream>>>(in, out, total4);
}

// Round 2
// 22.343 us; speedup vs baseline: 1.3810x; 1.3810x over previous
//
#include <hip/hip_runtime.h>

// MedianFilter2D: 3x3 median, reflect pad, [16,3,512,512] f32.
// Identity (transpose form): per ROW horizontal sorted triple over cols j-1..j+1
// (hmin,hmed,hmax); median9 = med3( max3(hmin over 3 rows),
//                                   med3(hmed over 3 rows),
//                                   min3(hmax over 3 rows) ).
// Each thread: one 4-column group x R=8 consecutive output rows, rolling the
// per-row triples so each input row is loaded once per thread.
// Read amplification (R+2)/R = 1.25x vs 3x for the row-per-thread version.

constexpr int Wd = 512;
constexpr int Hd = 512;
constexpr int R  = 8;   // output rows per thread

__device__ __forceinline__ float med3f(float a, float b, float c) {
    return __builtin_amdgcn_fmed3f(a, b, c);
}
__device__ __forceinline__ float min3f(float a, float b, float c) {
    return fminf(fminf(a, b), c);   // v_min3_f32
}
__device__ __forceinline__ float max3f(float a, float b, float c) {
    return fmaxf(fmaxf(a, b), c);   // v_max3_f32
}

struct Trip { float mn[4], md[4], mx[4]; };

__global__ __launch_bounds__(256) void MedianFilter2D_68745246540291_kernel(
    const float* __restrict__ in, float* __restrict__ out, int total) {
    int idx = blockIdx.x * blockDim.x + threadIdx.x;
    if (idx >= total) return;

    int cg = idx & 127;            // column group (4 cols each)
    int w4 = cg << 2;
    int rt = (idx >> 7) & 63;      // row tile within plane (H/R = 64)
    int r0 = rt * R;
    long plane = (long)(idx >> 13);

    const float* p = in  + plane * (long)(Hd * Wd);
    float*       q = out + plane * (long)(Hd * Wd);

    auto loadrow = [&](int g) -> Trip {
        int h = (g < 0) ? 1 : ((g > Hd - 1) ? Hd - 2 : g);   // reflect
        const float* rp = p + (long)h * Wd;
        float4 c4 = *reinterpret_cast<const float4*>(rp + w4);
        float v0 = (w4 == 0)        ? rp[1]      : rp[w4 - 1];
        float v5 = (w4 + 4 >= Wd)   ? rp[Wd - 2] : rp[w4 + 4];
        float v[6] = { v0, c4.x, c4.y, c4.z, c4.w, v5 };
        Trip t;
#pragma unroll
        for (int j = 0; j < 4; ++j) {
            t.mn[j] = min3f(v[j], v[j + 1], v[j + 2]);
            t.md[j] = med3f(v[j], v[j + 1], v[j + 2]);
            t.mx[j] = max3f(v[j], v[j + 1], v[j + 2]);
        }
        return t;
    };

    Trip t0 = loadrow(r0 - 1);
    Trip t1 = loadrow(r0);
#pragma unroll
    for (int i = 0; i < R; ++i) {
        Trip t2 = loadrow(r0 + i + 1);
        float4 o;
        float* op = &o.x;
#pragma unroll
        for (int j = 0; j < 4; ++j) {
            float lo = max3f(t0.mn[j], t1.mn[j], t2.mn[j]);
            float mi = med3f(t0.md[j], t1.md[j], t2.md[j]);
            float hi = min3f(t0.mx[j], t1.mx[j], t2.mx[j]);
            op[j] = med3f(lo, mi, hi);
        }
        *reinterpret_cast<float4*>(q + (long)(r0 + i) * Wd + w4) = o;
        t0 = t1;
        t1 = t2;
    }
}

extern "C" void kernel_launch(void* const* d_in, const int* in_sizes, int n_in,
                              void* d_out, int out_size, void* d_ws, size_t ws_size,
                              hipStream_t stream) {
    const float* in = (const float*)d_in[0];
    float* out = (float*)d_out;
    int total = out_size / (4 * R);            // threads: 4 cols x R rows each
    int block = 256;
    int grid = (total + block - 1) / block;    // 1536 blocks
    MedianFilter2D_68745246540291_kernel<<<grid, block, 0, stream>>>(in, out, total);
}

// Round 3
// 21.920 us; speedup vs baseline: 1.4076x; 1.0193x over previous
//
#include <hip/hip_runtime.h>

// MedianFilter2D: 3x3 median, reflect pad, [16,3,512,512] f32.
// Per-row horizontal sorted triple (hmin,hmed,hmax) over cols j-1..j+1;
// median9 = med3( max3(hmin x3 rows), med3(hmed x3 rows), min3(hmax x3 rows) ).
// Each thread: 4-column group x R=16 consecutive output rows, rolling the
// per-row triples. Read amplification (R+2)/R = 1.125x.

constexpr int Wd = 512;
constexpr int Hd = 512;
constexpr int R  = 16;  // output rows per thread

__device__ __forceinline__ float med3f(float a, float b, float c) {
    return __builtin_amdgcn_fmed3f(a, b, c);
}
__device__ __forceinline__ float min3f(float a, float b, float c) {
    return fminf(fminf(a, b), c);   // v_min3_f32
}
__device__ __forceinline__ float max3f(float a, float b, float c) {
    return fmaxf(fmaxf(a, b), c);   // v_max3_f32
}

struct Trip { float mn[4], md[4], mx[4]; };

__global__ __launch_bounds__(256) void MedianFilter2D_68745246540291_kernel(
    const float* __restrict__ in, float* __restrict__ out, int total) {
    int idx = blockIdx.x * blockDim.x + threadIdx.x;
    if (idx >= total) return;

    int cg = idx & 127;            // column group (4 cols each)
    int w4 = cg << 2;
    int rt = (idx >> 7) & 31;      // row tile within plane (H/R = 32)
    int r0 = rt * R;
    long plane = (long)(idx >> 12);

    const float* p = in  + plane * (long)(Hd * Wd);
    float*       q = out + plane * (long)(Hd * Wd);

    auto loadrow = [&](int g) -> Trip {
        int h = (g < 0) ? 1 : ((g > Hd - 1) ? Hd - 2 : g);   // reflect
        const float* rp = p + (long)h * Wd;
        float4 c4 = *reinterpret_cast<const float4*>(rp + w4);
        float v0 = (w4 == 0)        ? rp[1]      : rp[w4 - 1];
        float v5 = (w4 + 4 >= Wd)   ? rp[Wd - 2] : rp[w4 + 4];
        float v[6] = { v0, c4.x, c4.y, c4.z, c4.w, v5 };
        Trip t;
#pragma unroll
        for (int j = 0; j < 4; ++j) {
            t.mn[j] = min3f(v[j], v[j + 1], v[j + 2]);
            t.md[j] = med3f(v[j], v[j + 1], v[j + 2]);
            t.mx[j] = max3f(v[j], v[j + 1], v[j + 2]);
        }
        return t;
    };

    Trip t0 = loadrow(r0 - 1);
    Trip t1 = loadrow(r0);
#pragma unroll
    for (int i = 0; i < R; ++i) {
        Trip t2 = loadrow(r0 + i + 1);
        float4 o;
        float* op = &o.x;
#pragma unroll
        for (int j = 0; j < 4; ++j) {
            float lo = max3f(t0.mn[j], t1.mn[j], t2.mn[j]);
            float mi = med3f(t0.md[j], t1.md[j], t2.md[j]);
            float hi = min3f(t0.mx[j], t1.mx[j], t2.mx[j]);
            op[j] = med3f(lo, mi, hi);
        }
        *reinterpret_cast<float4*>(q + (long)(r0 + i) * Wd + w4) = o;
        t0 = t1;
        t1 = t2;
    }
}

extern "C" void kernel_launch(void* const* d_in, const int* in_sizes, int n_in,
                              void* d_out, int out_size, void* d_ws, size_t ws_size,
                              hipStream_t stream) {
    const float* in = (const float*)d_in[0];
    float* out = (float*)d_out;
    int total = out_size / (4 * R);            // threads: 4 cols x R rows each
    int block = 256;
    int grid = (total + block - 1) / block;    // 768 blocks
    MedianFilter2D_68745246540291_kernel<<<grid, block, 0, stream>>>(in, out, total);
}